// Round 1
// baseline (618.599 us; speedup 1.0000x reference)
//
#include <hip/hip_runtime.h>
#include <hip/hip_bf16.h>
#include <math.h>

#define BDIM 1024
#define CDIM 100000
#define DDIM 512
#define LDS_STRIDE 72   // 64 + 8 bf16 pad: even bank-quad distribution for ds_read_b128

typedef float f32x4 __attribute__((ext_vector_type(4)));
typedef short bf16x8 __attribute__((ext_vector_type(8)));

static __device__ __forceinline__ unsigned short f2bf(float f) {
    union { float f; unsigned int u; } v; v.f = f;
    unsigned int r = v.u + 0x7FFFu + ((v.u >> 16) & 1u);  // RNE
    return (unsigned short)(r >> 16);
}

static __device__ __forceinline__ uint4 pack8(const float4 p, const float4 q) {
    union { unsigned short u[8]; uint4 v; } pk;
    pk.u[0] = f2bf(p.x); pk.u[1] = f2bf(p.y); pk.u[2] = f2bf(p.z); pk.u[3] = f2bf(p.w);
    pk.u[4] = f2bf(q.x); pk.u[5] = f2bf(q.y); pk.u[6] = f2bf(q.z); pk.u[7] = f2bf(q.w);
    return pk.v;
}

// Normalize rows of x (fp32 [1024][512]) -> bf16 [1024][512] in ws.
// One wave per row: 64 lanes x 8 floats.
__global__ void xnorm_kernel(const float* __restrict__ x, unsigned short* __restrict__ xn) {
    const int row  = blockIdx.x * 4 + (threadIdx.x >> 6);
    const int lane = threadIdx.x & 63;
    const float* xr = x + row * DDIM;
    float4 a = *(const float4*)(xr + lane * 4);
    float4 b = *(const float4*)(xr + 256 + lane * 4);
    float s = a.x*a.x + a.y*a.y + a.z*a.z + a.w*a.w
            + b.x*b.x + b.y*b.y + b.z*b.z + b.w*b.w;
#pragma unroll
    for (int o = 32; o; o >>= 1) s += __shfl_xor(s, o);
    const float sc = 1.0f / fmaxf(sqrtf(s), 1e-12f);
    ushort4 o0, o1;
    o0.x = f2bf(a.x * sc); o0.y = f2bf(a.y * sc); o0.z = f2bf(a.z * sc); o0.w = f2bf(a.w * sc);
    o1.x = f2bf(b.x * sc); o1.y = f2bf(b.y * sc); o1.z = f2bf(b.z * sc); o1.w = f2bf(b.w * sc);
    *(ushort4*)(xn + row * DDIM + lane * 4)       = o0;
    *(ushort4*)(xn + row * DDIM + 256 + lane * 4) = o1;
}

// Per-row 1/max(||w||, eps) -> sw[100000] in ws. One wave per row.
__global__ void wnorm_kernel(const float* __restrict__ w, float* __restrict__ sw) {
    const int row  = blockIdx.x * 4 + (threadIdx.x >> 6);
    const int lane = threadIdx.x & 63;
    const float* wr = w + (size_t)row * DDIM;
    float4 a = *(const float4*)(wr + lane * 4);
    float4 b = *(const float4*)(wr + 256 + lane * 4);
    float s = a.x*a.x + a.y*a.y + a.z*a.z + a.w*a.w
            + b.x*b.x + b.y*b.y + b.z*b.z + b.w*b.w;
#pragma unroll
    for (int o = 32; o; o >>= 1) s += __shfl_xor(s, o);
    if (lane == 0) sw[row] = 1.0f / fmaxf(sqrtf(s), 1e-12f);
}

// GEMM: out[b][c] = S * margin( (xn[b] . bf16(w[c])) * sw[c] )
// 128x128 tile, 4 waves (2x2), BK=64, double-buffered LDS, reg-staged B with
// on-the-fly fp32->bf16 convert. A from pre-normalized bf16 in ws.
__global__ __launch_bounds__(256, 2)
void arc_gemm_kernel(const unsigned short* __restrict__ xn,
                     const float* __restrict__ w,
                     const float* __restrict__ sw,
                     const int* __restrict__ tgt,
                     float* __restrict__ out) {
    __shared__ unsigned short As[2][128 * LDS_STRIDE];
    __shared__ unsigned short Bs[2][128 * LDS_STRIDE];

    const int t    = threadIdx.x;
    const int lane = t & 63;
    const int wid  = t >> 6;
    const int mt   = blockIdx.x & 7;     // m-inner: 8 blocks share one weight tile (L3 reuse)
    const int nt   = blockIdx.x >> 3;
    const int m0   = mt * 128;
    const int n0   = nt * 128;
    const int wm   = (wid & 1) * 64;
    const int wn   = (wid >> 1) * 64;

    // staging: 2 threads per row, 32 k-elems each
    const int sr = t >> 1;
    const int sk = (t & 1) * 32;

    const unsigned short* Ag = xn + (m0 + sr) * DDIM + sk;
    int brow = n0 + sr; brow = brow < CDIM ? brow : (CDIM - 1);   // clamp tail loads
    const float* Bg = w + (size_t)brow * DDIM + sk;

    f32x4 acc[4][4] = {};
    uint4  ar[4];
    float4 br[8];

#define LOAD_TILE(kk) do {                                                     \
    _Pragma("unroll") for (int i = 0; i < 4; ++i)                              \
        ar[i] = *(const uint4*)(Ag + (kk) + i * 8);                            \
    _Pragma("unroll") for (int i = 0; i < 8; ++i)                              \
        br[i] = *(const float4*)(Bg + (kk) + i * 4);                           \
} while (0)

#define STORE_TILE(bufi) do {                                                  \
    unsigned short* ab = &As[bufi][sr * LDS_STRIDE + sk];                      \
    unsigned short* bb = &Bs[bufi][sr * LDS_STRIDE + sk];                      \
    _Pragma("unroll") for (int i = 0; i < 4; ++i)                              \
        *(uint4*)(ab + i * 8) = ar[i];                                         \
    _Pragma("unroll") for (int j = 0; j < 4; ++j)                              \
        *(uint4*)(bb + j * 8) = pack8(br[2 * j], br[2 * j + 1]);               \
} while (0)

#define MFMA_STEP(bufi) do {                                                   \
    _Pragma("unroll") for (int hk = 0; hk < 2; ++hk) {                         \
        bf16x8 av[4], bv[4];                                                   \
        const int ko = hk * 32 + (lane >> 4) * 8;                              \
        _Pragma("unroll") for (int f = 0; f < 4; ++f) {                        \
            av[f] = *(const bf16x8*)(&As[bufi][(wm + f * 16 + (lane & 15)) * LDS_STRIDE + ko]); \
            bv[f] = *(const bf16x8*)(&Bs[bufi][(wn + f * 16 + (lane & 15)) * LDS_STRIDE + ko]); \
        }                                                                      \
        _Pragma("unroll") for (int mf = 0; mf < 4; ++mf)                       \
            _Pragma("unroll") for (int nf = 0; nf < 4; ++nf)                   \
                acc[mf][nf] = __builtin_amdgcn_mfma_f32_16x16x32_bf16(         \
                    av[mf], bv[nf], acc[mf][nf], 0, 0, 0);                     \
    }                                                                          \
} while (0)

    LOAD_TILE(0);
    STORE_TILE(0);
#pragma unroll
    for (int ks = 0; ks < 8; ++ks) {
        const int cur = ks & 1;
        if (ks < 7) LOAD_TILE((ks + 1) * 64);   // prefetch next tile into regs
        __syncthreads();                        // buf[cur] writes visible
        MFMA_STEP(cur);
        if (ks < 7) STORE_TILE(cur ^ 1);        // stage next tile while others compute
    }

    // Epilogue: cos = acc * sw[col]; margin at col == target[row]; * S; tail-predicated.
    float swv[4];
    int   gcv[4];
#pragma unroll
    for (int nf = 0; nf < 4; ++nf) {
        int gc = n0 + wn + nf * 16 + (lane & 15);
        gcv[nf] = gc;
        swv[nf] = sw[gc < CDIM ? gc : (CDIM - 1)];
    }
#pragma unroll
    for (int mf = 0; mf < 4; ++mf) {
#pragma unroll
        for (int j = 0; j < 4; ++j) {
            const int grow = m0 + wm + mf * 16 + (lane >> 4) * 4 + j;
            const int tg = tgt[grow];
            float* orow = out + (size_t)grow * CDIM;
#pragma unroll
            for (int nf = 0; nf < 4; ++nf) {
                const int gc = gcv[nf];
                if (gc < CDIM) {
                    float v = acc[mf][nf][j] * swv[nf];
                    if (gc == tg) {
                        float cv = fminf(fmaxf(v, -1.0f), 1.0f);
                        if (v > 0.0f)   // easy_margin cond: cos_t > 0
                            v = cv * 0.87758256189037276f
                              - sqrtf(fmaxf(0.0f, 1.0f - cv * cv)) * 0.47942553860420301f;
                    }
                    orow[gc] = v * 64.0f;
                }
            }
        }
    }
#undef LOAD_TILE
#undef STORE_TILE
#undef MFMA_STEP
}

extern "C" void kernel_launch(void* const* d_in, const int* in_sizes, int n_in,
                              void* d_out, int out_size, void* d_ws, size_t ws_size,
                              hipStream_t stream) {
    const float* x   = (const float*)d_in[0];
    const float* w   = (const float*)d_in[1];
    const int*   tgt = (const int*)d_in[2];
    float* out = (float*)d_out;

    unsigned short* xn = (unsigned short*)d_ws;                         // 1 MB
    float* sw = (float*)((char*)d_ws + (size_t)BDIM * DDIM * 2);        // 400 KB

    hipLaunchKernelGGL(xnorm_kernel, dim3(BDIM / 4), dim3(256), 0, stream, x, xn);
    hipLaunchKernelGGL(wnorm_kernel, dim3(CDIM / 4), dim3(256), 0, stream, w, sw);

    const int ntiles = (CDIM + 127) / 128;   // 782 (last tile 32 valid cols)
    hipLaunchKernelGGL(arc_gemm_kernel, dim3(8 * ntiles), dim3(256), 0, stream,
                       xn, w, sw, tgt, out);
}